// Round 2
// baseline (151.494 us; speedup 1.0000x reference)
//
#include <hip/hip_runtime.h>
#include <hip/hip_bf16.h>
#include <stdint.h>

#define N_ROWS 8192
#define DIM 512
#define NLAB 512
#define MARGIN_F 0.35f
#define NBLK 64                        // 8192/128 row-blocks
#define NPURE 1953                     // tiles with bi-bj >= 2
#define NDIAG 127                      // diagonal (64) + subdiagonal (63)
#define NTILE (NPURE + NDIAG)          // 2080
#define ROWSTAT_BLOCKS (N_ROWS / 4)    // 2048

typedef __attribute__((ext_vector_type(4))) float floatx4;
typedef __attribute__((ext_vector_type(8))) int intx8;

// order-preserving float->uint map (for atomicMin/Max on floats)
__device__ __forceinline__ unsigned enc_f(float f) {
    unsigned u = __float_as_uint(f);
    return (u & 0x80000000u) ? ~u : (u | 0x80000000u);
}
__device__ __forceinline__ float dec_f(unsigned e) {
    unsigned u = (e & 0x80000000u) ? (e ^ 0x80000000u) : ~e;
    return __uint_as_float(u);
}

// Single block: histogram of labels + exclusive scan -> offsets, zero rank counters + out.
__global__ __launch_bounds__(512) void histscan_kernel(const int* __restrict__ label,
                                                       int* __restrict__ offsetArr,
                                                       int* __restrict__ cnt,
                                                       float* __restrict__ out) {
    __shared__ int h[NLAB];
    __shared__ int sc[NLAB];
    int t = threadIdx.x;
    h[t] = 0;
    __syncthreads();
    for (int i = t; i < N_ROWS; i += 512) atomicAdd(&h[label[i]], 1);
    __syncthreads();
    int v = h[t];
    sc[t] = v;
    __syncthreads();
    for (int d = 1; d < NLAB; d <<= 1) {
        int add = (t >= d) ? sc[t - d] : 0;
        __syncthreads();
        sc[t] += add;
        __syncthreads();
    }
    offsetArr[t] = sc[t] - v;   // exclusive prefix
    cnt[t] = 0;
    if (t == 0) out[0] = 0.f;
}

// One wave per row: CE partial + fp8(e4m3) conversion scattered to label-sorted position.
// Also initializes minEnc/maxEnc.
__global__ __launch_bounds__(256) void rowstats_kernel(const float* __restrict__ x,
                                                       const int* __restrict__ label,
                                                       const int* __restrict__ offsetArr,
                                                       int* __restrict__ cnt,
                                                       unsigned char* __restrict__ a8,
                                                       int* __restrict__ sortedLabel,
                                                       float* __restrict__ cePartial,
                                                       unsigned* __restrict__ minEnc,
                                                       unsigned* __restrict__ maxEnc) {
    int gid = blockIdx.x * 256 + threadIdx.x;
    if (gid < N_ROWS) { minEnc[gid] = 0xFFFFFFFFu; maxEnc[gid] = 0u; }

    int w = threadIdx.x >> 6;
    int row = blockIdx.x * 4 + w;
    int l = threadIdx.x & 63;
    const float* xr = x + (size_t)row * DIM;
    float4 v0 = ((const float4*)xr)[2 * l];
    float4 v1 = ((const float4*)xr)[2 * l + 1];
    float vals[8] = {v0.x, v0.y, v0.z, v0.w, v1.x, v1.y, v1.z, v1.w};

    float mx = vals[0];
#pragma unroll
    for (int i = 1; i < 8; i++) mx = fmaxf(mx, vals[i]);
#pragma unroll
    for (int s = 1; s < 64; s <<= 1) mx = fmaxf(mx, __shfl_xor(mx, s, 64));

    float se = 0.f;
#pragma unroll
    for (int i = 0; i < 8; i++) se += expf(vals[i] - mx);
#pragma unroll
    for (int s = 1; s < 64; s <<= 1) se += __shfl_xor(se, s, 64);

    // sorted position for this row (counting-sort rank)
    int pos = 0;
    if (l == 0) {
        int lab = label[row];
        pos = offsetArr[lab] + atomicAdd(&cnt[lab], 1);
        sortedLabel[pos] = lab;
    }
    pos = __shfl(pos, 0, 64);

    // pack 8 fp8 e4m3 and store 8B to the sorted slot
    int w0 = __builtin_amdgcn_cvt_pk_fp8_f32(vals[0], vals[1], 0, false);
    w0 = __builtin_amdgcn_cvt_pk_fp8_f32(vals[2], vals[3], w0, true);
    int w1 = __builtin_amdgcn_cvt_pk_fp8_f32(vals[4], vals[5], 0, false);
    w1 = __builtin_amdgcn_cvt_pk_fp8_f32(vals[6], vals[7], w1, true);
    ((uint2*)(a8 + (size_t)pos * DIM))[l] = make_uint2((unsigned)w0, (unsigned)w1);

    __shared__ float wsum[4];
    if (l == 0) {
        float tl = xr[label[row]];
        wsum[w] = mx + logf(se) - tl;
    }
    __syncthreads();
    if (threadIdx.x == 0)
        cePartial[blockIdx.x] = wsum[0] + wsum[1] + wsum[2] + wsum[3];
}

// Merged GEMM on fp8: blocks [0, NDIAG) diag/subdiag tiles (mixed epilogue),
// blocks [NDIAG, NTILE) pure tiles (max-only). 128x128 tile,
// mfma_scale 16x16x128 f8f6f4 (scale=1.0), 2x2 waves x 4x4 frags.
//
// R2 change: operand LDS ELIMINATED. a8 is 4 MB = L2-resident on every XCD,
// so LDS staging saved no HBM traffic, only the 2x wave-pair redundancy --
// at the cost of 8 barriers + full vmcnt(0) drains per block on a 4-iter
// K-loop (barrier-serialization-bound: ~40 us vs ~8 us floors).
// Now each fragment = two global_load_dwordx4 at compile-time-constant
// offsets straight from L2. Zero barriers in the K-loop, zero LDS staging,
// LDS down to 5 KB (reduction scratch only). Occupancy stays VGPR-bound at
// 3 blocks/CU. New floor: L2-BW at 2x traffic (~15 us chip-wide).
// R1 post-mortem: dbuf at 2 blocks/CU regressed (110.3 -> 119.5); occupancy
// is what hides latency here, never trade it for pipeline depth at K=512.
__global__ __launch_bounds__(256, 3) void gemm_kernel(const unsigned char* __restrict__ A,
                                                      const int* __restrict__ sortedLabel,
                                                      unsigned* __restrict__ minEnc,
                                                      unsigned* __restrict__ maxEnc) {
    __shared__ float redA[128][2], redB[128][2];       // Imx / Jmx
    __shared__ float redImn[128][2], redJmn[128][2];   // Imn / Jmn (diag only)
    __shared__ int labi[128], labj[128];               // labels (diag only)

    int b = blockIdx.x;
    bool diag = (b < NDIAG);
    int bi, bj;
    if (diag) {
        bi = (b < 64) ? b : (b - 63);
        bj = (b < 64) ? b : (b - 64);
    } else {
        int p = b - NDIAG;
        int ci = (int)((sqrtf(8.0f * (float)p + 1.0f) - 1.0f) * 0.5f);
        while ((ci + 1) * (ci + 2) / 2 <= p) ci++;
        while (ci * (ci + 1) / 2 > p) ci--;
        bj = p - ci * (ci + 1) / 2;
        bi = ci + 2;
    }
    int ibase = bi * 128, jbase = bj * 128;

    int t = threadIdx.x;
    int w = t >> 6, l = t & 63;
    int wm = w >> 1, wn = w & 1;
    int q = l >> 4, lm = l & 15;

    // diag: kick off label loads early; they complete under the K-loop.
    if (diag) {
        if (t < 128) labi[t] = sortedLabel[ibase + t];
        else labj[t - 128] = sortedLabel[jbase + t - 128];
    }

    floatx4 acc[4][4];
#pragma unroll
    for (int a = 0; a < 4; a++)
#pragma unroll
        for (int c = 0; c < 4; c++) acc[a][c] = (floatx4)0.f;

    // Fragment layout for mfma_scale_f32_16x16x128_f8f6f4:
    // lane (q,lm) holds row lm, k = q*32 .. q*32+31  (two 16B chunks).
    // Per-lane base pointers; all tm/tn/kk offsets are compile-time constants
    // (int4 units): tm*16 rows * 512 B = tm*512, k-step kk*128 B = kk*8.
    const int4* pA = (const int4*)(A + (size_t)(ibase + wm * 64 + lm) * DIM + q * 32);
    const int4* pB = (const int4*)(A + (size_t)(jbase + wn * 64 + lm) * DIM + q * 32);

#pragma unroll
    for (int kk = 0; kk < 4; kk++) {
        intx8 bfv[4];
#pragma unroll
        for (int tn = 0; tn < 4; tn++) {
            int4 lo = pB[tn * 512 + kk * 8];
            int4 hi = pB[tn * 512 + kk * 8 + 1];
            intx8 v;
            v[0] = lo.x; v[1] = lo.y; v[2] = lo.z; v[3] = lo.w;
            v[4] = hi.x; v[5] = hi.y; v[6] = hi.z; v[7] = hi.w;
            bfv[tn] = v;
        }
#pragma unroll
        for (int tm = 0; tm < 4; tm++) {
            int4 lo = pA[tm * 512 + kk * 8];
            int4 hi = pA[tm * 512 + kk * 8 + 1];
            intx8 af;
            af[0] = lo.x; af[1] = lo.y; af[2] = lo.z; af[3] = lo.w;
            af[4] = hi.x; af[5] = hi.y; af[6] = hi.z; af[7] = hi.w;
#pragma unroll
            for (int tn = 0; tn < 4; tn++)
                acc[tm][tn] = __builtin_amdgcn_mfma_scale_f32_16x16x128_f8f6f4(
                    af, bfv[tn], acc[tm][tn], 0, 0,      // cbsz=fp8, blgp=fp8
                    0, 0x7F7F7F7F,                        // scale A = 1.0 (any byte)
                    0, 0x7F7F7F7F);                       // scale B = 1.0
        }
    }

    // C/D layout: col = lane&15, row = (lane>>4)*4 + reg [m89/m91; shape-determined]
    const float INF = __builtin_inff();

    if (!diag) {
        // ---- max-only epilogue (no labels) ----
        float mxJ[4];
#pragma unroll
        for (int tn = 0; tn < 4; tn++) mxJ[tn] = -INF;
#pragma unroll
        for (int tm = 0; tm < 4; tm++) {
#pragma unroll
            for (int r = 0; r < 4; r++) {
                int row_l = wm * 64 + tm * 16 + q * 4 + r;
                float mxI = -INF;
#pragma unroll
                for (int tn = 0; tn < 4; tn++) {
                    float v = acc[tm][tn][r];
                    mxI = fmaxf(mxI, v);
                    mxJ[tn] = fmaxf(mxJ[tn], v);
                }
#pragma unroll
                for (int s = 1; s < 16; s <<= 1)
                    mxI = fmaxf(mxI, __shfl_xor(mxI, s, 64));
                if (lm == 0) redA[row_l][wn] = mxI;
            }
        }
#pragma unroll
        for (int tn = 0; tn < 4; tn++) {
#pragma unroll
            for (int s = 16; s < 64; s <<= 1)
                mxJ[tn] = fmaxf(mxJ[tn], __shfl_xor(mxJ[tn], s, 64));
            if (q == 0) redB[wn * 64 + tn * 16 + lm][wm] = mxJ[tn];
        }
        __syncthreads();
        if (t < 128) {
            atomicMax(&maxEnc[ibase + t], enc_f(fmaxf(redA[t][0], redA[t][1])));
            atomicMax(&maxEnc[jbase + t], enc_f(fmaxf(redB[t][0], redB[t][1])));
        }
    } else {
        // ---- mixed epilogue (min-same / max-diff) ----
        __syncthreads();   // labi/labj visible (loaded pre-K-loop)

        int jlab[4];
#pragma unroll
        for (int tn = 0; tn < 4; tn++) jlab[tn] = labj[wn * 64 + tn * 16 + lm];

        float mnJ[4], mxJ[4];
#pragma unroll
        for (int tn = 0; tn < 4; tn++) { mnJ[tn] = INF; mxJ[tn] = -INF; }

#pragma unroll
        for (int tm = 0; tm < 4; tm++) {
#pragma unroll
            for (int r = 0; r < 4; r++) {
                int row_l = wm * 64 + tm * 16 + q * 4 + r;
                int il = labi[row_l];
                float mnI = INF, mxI = -INF;
#pragma unroll
                for (int tn = 0; tn < 4; tn++) {
                    float v = acc[tm][tn][r];
                    bool same = (jlab[tn] == il);
                    float vs = same ? v : INF;
                    float vd = same ? -INF : v;
                    mnI = fminf(mnI, vs);
                    mxI = fmaxf(mxI, vd);
                    mnJ[tn] = fminf(mnJ[tn], vs);
                    mxJ[tn] = fmaxf(mxJ[tn], vd);
                }
#pragma unroll
                for (int s = 1; s < 16; s <<= 1) {
                    mnI = fminf(mnI, __shfl_xor(mnI, s, 64));
                    mxI = fmaxf(mxI, __shfl_xor(mxI, s, 64));
                }
                if (lm == 0) { redImn[row_l][wn] = mnI; redA[row_l][wn] = mxI; }
            }
        }
#pragma unroll
        for (int tn = 0; tn < 4; tn++) {
#pragma unroll
            for (int s = 16; s < 64; s <<= 1) {
                mnJ[tn] = fminf(mnJ[tn], __shfl_xor(mnJ[tn], s, 64));
                mxJ[tn] = fmaxf(mxJ[tn], __shfl_xor(mxJ[tn], s, 64));
            }
            if (q == 0) {
                int col_l = wn * 64 + tn * 16 + lm;
                redJmn[col_l][wm] = mnJ[tn];
                redB[col_l][wm] = mxJ[tn];
            }
        }
        __syncthreads();
        if (t < 128) {
            atomicMin(&minEnc[ibase + t], enc_f(fminf(redImn[t][0], redImn[t][1])));
            atomicMax(&maxEnc[ibase + t], enc_f(fmaxf(redA[t][0], redA[t][1])));
            atomicMin(&minEnc[jbase + t], enc_f(fminf(redJmn[t][0], redJmn[t][1])));
            atomicMax(&maxEnc[jbase + t], enc_f(fmaxf(redB[t][0], redB[t][1])));
        }
    }
}

// 32 blocks; one float atomicAdd per block into pre-zeroed out[0].
__global__ __launch_bounds__(256) void finalize_kernel(const unsigned* __restrict__ minEnc,
                                                       const unsigned* __restrict__ maxEnc,
                                                       const float* __restrict__ cePartial,
                                                       float* __restrict__ out) {
    int gid = blockIdx.x * 256 + threadIdx.x;   // 8192 threads total
    float mn = dec_f(minEnc[gid]);
    float mxv = dec_f(maxEnc[gid]);
    // pos - neg = 2*(max_diff G - min_same G); sq_i cancels, sq_j ≈ 1 (dev ~1e-7)
    float s = fmaxf(2.0f * (mxv - mn) + MARGIN_F, 0.f);
    if (gid < ROWSTAT_BLOCKS) s += cePartial[gid];
#pragma unroll
    for (int sh = 1; sh < 64; sh <<= 1) s += __shfl_xor(s, sh, 64);
    __shared__ float red[4];
    int w = threadIdx.x >> 6, l = threadIdx.x & 63;
    if (l == 0) red[w] = s;
    __syncthreads();
    if (threadIdx.x == 0)
        atomicAdd(out, (red[0] + red[1] + red[2] + red[3]) * (1.0f / (float)N_ROWS));
}

extern "C" void kernel_launch(void* const* d_in, const int* in_sizes, int n_in,
                              void* d_out, int out_size, void* d_ws, size_t ws_size,
                              hipStream_t stream) {
    const float* x = (const float*)d_in[0];
    const int* label = (const int*)d_in[1];
    float* out = (float*)d_out;

    char* ws = (char*)d_ws;
    unsigned char* a8 = (unsigned char*)ws;                      // 4 MB fp8 sorted copy
    char* p = ws + (size_t)N_ROWS * DIM;
    unsigned* minEnc = (unsigned*)p;            p += N_ROWS * 4;
    unsigned* maxEnc = (unsigned*)p;            p += N_ROWS * 4;
    float* cePartial = (float*)p;               p += ROWSTAT_BLOCKS * 4;
    int* offsetArr = (int*)p;                   p += NLAB * 4;
    int* cnt = (int*)p;                         p += NLAB * 4;
    int* sortedLabel = (int*)p;                 p += N_ROWS * 4;

    histscan_kernel<<<1, 512, 0, stream>>>(label, offsetArr, cnt, out);
    rowstats_kernel<<<ROWSTAT_BLOCKS, 256, 0, stream>>>(x, label, offsetArr, cnt, a8,
                                                        sortedLabel, cePartial, minEnc, maxEnc);
    gemm_kernel<<<NTILE, 256, 0, stream>>>(a8, sortedLabel, minEnc, maxEnc);
    finalize_kernel<<<32, 256, 0, stream>>>(minEnc, maxEnc, cePartial, out);
}

// Round 3
// 116.732 us; speedup vs baseline: 1.2978x; 1.2978x over previous
//
#include <hip/hip_runtime.h>
#include <hip/hip_bf16.h>
#include <stdint.h>

#define N_ROWS 8192
#define DIM 512
#define NLAB 512
#define MARGIN_F 0.35f
#define NBLK 64                        // 8192/128 row-blocks
#define NPURE 1953                     // tiles with bi-bj >= 2
#define NDIAG 127                      // diagonal (64) + subdiagonal (63)
#define NTILE (NPURE + NDIAG)          // 2080
#define ROWSTAT_BLOCKS (N_ROWS / 4)    // 2048

typedef __attribute__((ext_vector_type(4))) float floatx4;
typedef __attribute__((ext_vector_type(16))) float floatx16;
typedef __attribute__((ext_vector_type(8))) int intx8;

// order-preserving float->uint map (for atomicMin/Max on floats)
__device__ __forceinline__ unsigned enc_f(float f) {
    unsigned u = __float_as_uint(f);
    return (u & 0x80000000u) ? ~u : (u | 0x80000000u);
}
__device__ __forceinline__ float dec_f(unsigned e) {
    unsigned u = (e & 0x80000000u) ? (e ^ 0x80000000u) : ~e;
    return __uint_as_float(u);
}

__device__ __forceinline__ void load_lds16(const void* g, void* l) {
    __builtin_amdgcn_global_load_lds((__attribute__((address_space(1))) void*)(void*)g,
                                     (__attribute__((address_space(3))) void*)l, 16, 0, 0);
}

// Single block: histogram of labels + exclusive scan -> offsets, zero rank counters + out.
__global__ __launch_bounds__(512) void histscan_kernel(const int* __restrict__ label,
                                                       int* __restrict__ offsetArr,
                                                       int* __restrict__ cnt,
                                                       float* __restrict__ out) {
    __shared__ int h[NLAB];
    __shared__ int sc[NLAB];
    int t = threadIdx.x;
    h[t] = 0;
    __syncthreads();
    for (int i = t; i < N_ROWS; i += 512) atomicAdd(&h[label[i]], 1);
    __syncthreads();
    int v = h[t];
    sc[t] = v;
    __syncthreads();
    for (int d = 1; d < NLAB; d <<= 1) {
        int add = (t >= d) ? sc[t - d] : 0;
        __syncthreads();
        sc[t] += add;
        __syncthreads();
    }
    offsetArr[t] = sc[t] - v;   // exclusive prefix
    cnt[t] = 0;
    if (t == 0) out[0] = 0.f;
}

// One wave per row: CE partial + fp8(e4m3) conversion scattered to label-sorted position.
// Also initializes minEnc/maxEnc.
__global__ __launch_bounds__(256) void rowstats_kernel(const float* __restrict__ x,
                                                       const int* __restrict__ label,
                                                       const int* __restrict__ offsetArr,
                                                       int* __restrict__ cnt,
                                                       unsigned char* __restrict__ a8,
                                                       int* __restrict__ sortedLabel,
                                                       float* __restrict__ cePartial,
                                                       unsigned* __restrict__ minEnc,
                                                       unsigned* __restrict__ maxEnc) {
    int gid = blockIdx.x * 256 + threadIdx.x;
    if (gid < N_ROWS) { minEnc[gid] = 0xFFFFFFFFu; maxEnc[gid] = 0u; }

    int w = threadIdx.x >> 6;
    int row = blockIdx.x * 4 + w;
    int l = threadIdx.x & 63;
    const float* xr = x + (size_t)row * DIM;
    float4 v0 = ((const float4*)xr)[2 * l];
    float4 v1 = ((const float4*)xr)[2 * l + 1];
    float vals[8] = {v0.x, v0.y, v0.z, v0.w, v1.x, v1.y, v1.z, v1.w};

    float mx = vals[0];
#pragma unroll
    for (int i = 1; i < 8; i++) mx = fmaxf(mx, vals[i]);
#pragma unroll
    for (int s = 1; s < 64; s <<= 1) mx = fmaxf(mx, __shfl_xor(mx, s, 64));

    float se = 0.f;
#pragma unroll
    for (int i = 0; i < 8; i++) se += expf(vals[i] - mx);
#pragma unroll
    for (int s = 1; s < 64; s <<= 1) se += __shfl_xor(se, s, 64);

    // sorted position for this row (counting-sort rank)
    int pos = 0;
    if (l == 0) {
        int lab = label[row];
        pos = offsetArr[lab] + atomicAdd(&cnt[lab], 1);
        sortedLabel[pos] = lab;
    }
    pos = __shfl(pos, 0, 64);

    // pack 8 fp8 e4m3 and store 8B to the sorted slot
    int w0 = __builtin_amdgcn_cvt_pk_fp8_f32(vals[0], vals[1], 0, false);
    w0 = __builtin_amdgcn_cvt_pk_fp8_f32(vals[2], vals[3], w0, true);
    int w1 = __builtin_amdgcn_cvt_pk_fp8_f32(vals[4], vals[5], 0, false);
    w1 = __builtin_amdgcn_cvt_pk_fp8_f32(vals[6], vals[7], w1, true);
    ((uint2*)(a8 + (size_t)pos * DIM))[l] = make_uint2((unsigned)w0, (unsigned)w1);

    __shared__ float wsum[4];
    if (l == 0) {
        float tl = xr[label[row]];
        wsum[w] = mx + logf(se) - tl;
    }
    __syncthreads();
    if (threadIdx.x == 0)
        cePartial[blockIdx.x] = wsum[0] + wsum[1] + wsum[2] + wsum[3];
}

// Merged GEMM on fp8. R3 structure:
//   - mfma_scale 32x32x64 f8f6f4 (same MX rate as 16x16x128, m59: 4686 TF),
//     so BK=64 and per-buffer tiles are 128x64 = 8 KB.
//   - FULL double-buffer of As+Bs in 32 KB (R0's single-buffer footprint):
//     per kk: STAGE(k+1 -> alt) issued first, compute(k) from cur, ONE barrier.
//     The barrier's vmcnt(0) drain lands a full MFMA phase after load issue
//     (R0 exposed a whole L2 round-trip per kk: loads issued right before drain).
//   - 2x2 waves, each 64x64 output = 2x2 frags of 32x32 -> acc 64 AGPR, but
//     inner arch working set is only a+b0+b1 = 24 regs -> __launch_bounds__(256,4)
//     targets 4 blocks/CU (LDS 4x37.9 = 152 <= 160 KiB; grid rounds 2.71 -> 2.03).
//   - LDS swizzle for 64B rows: chunk ^= (row>>1)&3 (16B granule); wave-read
//     bank spread verified even (8 accesses per bank-group) -> conflict-free.
// R1 post-mortem: dbuf at 2 blk/CU regressed; R2: L2-direct frags = 8% MfmaUtil.
// Fallback if (256,4) spills: relax to (256,3).
__global__ __launch_bounds__(256, 4) void gemm_kernel(const unsigned char* __restrict__ A,
                                                      const int* __restrict__ sortedLabel,
                                                      unsigned* __restrict__ minEnc,
                                                      unsigned* __restrict__ maxEnc) {
    __shared__ unsigned char As[2][128 * 64];   // 2 x 8 KB
    __shared__ unsigned char Bs[2][128 * 64];   // 2 x 8 KB
    __shared__ float redA[128][2], redB[128][2];       // Imx / Jmx
    __shared__ float redImn[128][2], redJmn[128][2];   // Imn / Jmn (diag only)
    __shared__ int labi[128], labj[128];               // labels (diag only)

    int b = blockIdx.x;
    bool diag = (b < NDIAG);
    int bi, bj;
    if (diag) {
        bi = (b < 64) ? b : (b - 63);
        bj = (b < 64) ? b : (b - 64);
    } else {
        int p = b - NDIAG;
        int ci = (int)((sqrtf(8.0f * (float)p + 1.0f) - 1.0f) * 0.5f);
        while ((ci + 1) * (ci + 2) / 2 <= p) ci++;
        while (ci * (ci + 1) / 2 > p) ci--;
        bj = p - ci * (ci + 1) / 2;
        bi = ci + 2;
    }
    int ibase = bi * 128, jbase = bj * 128;

    int t = threadIdx.x;
    int w = t >> 6, l = t & 63;
    int wm = w >> 1, wn = w & 1;
    int cl = l & 31;        // col/row lane within a 32x32 frag
    int hi = l >> 5;        // k-half select

    // diag: label loads issued early; first barrier makes them visible.
    if (diag) {
        if (t < 128) labi[t] = sortedLabel[ibase + t];
        else labj[t - 128] = sortedLabel[jbase + t - 128];
    }

    floatx16 acc[2][2];
#pragma unroll
    for (int a = 0; a < 2; a++)
#pragma unroll
        for (int c = 0; c < 2; c++) acc[a][c] = (floatx16)0.f;

    // Staging geometry: slot s = t + 256*i covers 512 slots of 16B = 8 KB tile.
    // LDS layout linear (gl_lds requirement); SOURCE pre-swizzled so that the
    // stored chunk at row r, slot c holds logical chunk c ^ ((r>>1)&3).
    int s0 = t, s1 = t + 256;
    int r0_ = s0 >> 2, r1_ = s1 >> 2;
    int c0_ = (s0 & 3) ^ ((r0_ >> 1) & 3);
    int c1_ = (s1 & 3) ^ ((r1_ >> 1) & 3);
    const unsigned char* srcA0 = A + (size_t)(ibase + r0_) * DIM + c0_ * 16;
    const unsigned char* srcA1 = A + (size_t)(ibase + r1_) * DIM + c1_ * 16;
    const unsigned char* srcB0 = A + (size_t)(jbase + r0_) * DIM + c0_ * 16;
    const unsigned char* srcB1 = A + (size_t)(jbase + r1_) * DIM + c1_ * 16;
    int ldo0 = s0 * 16, ldo1 = s1 * 16;

#define STAGE(KK, BUF)                                      \
    {                                                       \
        load_lds16(srcA0 + (KK) * 64, As[BUF] + ldo0);      \
        load_lds16(srcA1 + (KK) * 64, As[BUF] + ldo1);      \
        load_lds16(srcB0 + (KK) * 64, Bs[BUF] + ldo0);      \
        load_lds16(srcB1 + (KK) * 64, Bs[BUF] + ldo1);      \
    }

    STAGE(0, 0);
    __syncthreads();   // buf0 ready (prologue drain exposed once)

#pragma unroll
    for (int kk = 0; kk < 8; kk++) {
        int cur = kk & 1;
        if (kk < 7) STAGE(kk + 1, cur ^ 1);   // prefetch: lands during MFMA below

        // B fragments: lane holds col cl of j-rows, k = hi*32..hi*32+31 (2 chunks)
        intx8 b0, b1;
        {
            int r = wn * 64 + cl;
            int f = (r >> 1) & 3;
            const int4* rp = (const int4*)(Bs[cur] + r * 64);
            int4 lo = rp[(2 * hi) ^ f];
            int4 h4 = rp[(2 * hi + 1) ^ f];
            b0[0] = lo.x; b0[1] = lo.y; b0[2] = lo.z; b0[3] = lo.w;
            b0[4] = h4.x; b0[5] = h4.y; b0[6] = h4.z; b0[7] = h4.w;
        }
        {
            int r = wn * 64 + 32 + cl;
            int f = (r >> 1) & 3;
            const int4* rp = (const int4*)(Bs[cur] + r * 64);
            int4 lo = rp[(2 * hi) ^ f];
            int4 h4 = rp[(2 * hi + 1) ^ f];
            b1[0] = lo.x; b1[1] = lo.y; b1[2] = lo.z; b1[3] = lo.w;
            b1[4] = h4.x; b1[5] = h4.y; b1[6] = h4.z; b1[7] = h4.w;
        }
#pragma unroll
        for (int tm = 0; tm < 2; tm++) {
            int r = wm * 64 + tm * 32 + cl;
            int f = (r >> 1) & 3;
            const int4* rp = (const int4*)(As[cur] + r * 64);
            int4 lo = rp[(2 * hi) ^ f];
            int4 h4 = rp[(2 * hi + 1) ^ f];
            intx8 a;
            a[0] = lo.x; a[1] = lo.y; a[2] = lo.z; a[3] = lo.w;
            a[4] = h4.x; a[5] = h4.y; a[6] = h4.z; a[7] = h4.w;
            acc[tm][0] = __builtin_amdgcn_mfma_scale_f32_32x32x64_f8f6f4(
                a, b0, acc[tm][0], 0, 0, 0, 0x7F7F7F7F, 0, 0x7F7F7F7F);
            acc[tm][1] = __builtin_amdgcn_mfma_scale_f32_32x32x64_f8f6f4(
                a, b1, acc[tm][1], 0, 0, 0, 0x7F7F7F7F, 0, 0x7F7F7F7F);
        }
        __syncthreads();   // drains prefetch (issued before compute) + guards flip
    }
#undef STAGE

    // C/D layout 32x32: col = lane&31, row = (reg&3) + 8*(reg>>2) + 4*(lane>>5)
    const float INF = __builtin_inff();
    int rbase = 4 * hi;   // row contribution of the lane's k-half

    if (!diag) {
        // ---- max-only epilogue ----
        float mxJ0 = -INF, mxJ1 = -INF;
#pragma unroll
        for (int tm = 0; tm < 2; tm++) {
            float rm[16];
#pragma unroll
            for (int r = 0; r < 16; r++) {
                float v0 = acc[tm][0][r], v1 = acc[tm][1][r];
                rm[r] = fmaxf(v0, v1);
                mxJ0 = fmaxf(mxJ0, v0);
                mxJ1 = fmaxf(mxJ1, v1);
            }
#pragma unroll
            for (int r = 0; r < 16; r++)
#pragma unroll
                for (int s = 1; s < 32; s <<= 1)
                    rm[r] = fmaxf(rm[r], __shfl_xor(rm[r], s, 64));
            if (cl == 0) {
#pragma unroll
                for (int r = 0; r < 16; r++)
                    redA[wm * 64 + tm * 32 + (r & 3) + 8 * (r >> 2) + rbase][wn] = rm[r];
            }
        }
        mxJ0 = fmaxf(mxJ0, __shfl_xor(mxJ0, 32, 64));
        mxJ1 = fmaxf(mxJ1, __shfl_xor(mxJ1, 32, 64));
        if (hi == 0) {
            redB[wn * 64 + cl][wm] = mxJ0;
            redB[wn * 64 + 32 + cl][wm] = mxJ1;
        }
        __syncthreads();
        if (t < 128) {
            atomicMax(&maxEnc[ibase + t], enc_f(fmaxf(redA[t][0], redA[t][1])));
            atomicMax(&maxEnc[jbase + t], enc_f(fmaxf(redB[t][0], redB[t][1])));
        }
    } else {
        // ---- mixed epilogue (min-same / max-diff) ----
        int jl0 = labj[wn * 64 + cl];
        int jl1 = labj[wn * 64 + 32 + cl];
        float mnJ0 = INF, mnJ1 = INF, mxJ0 = -INF, mxJ1 = -INF;
#pragma unroll
        for (int tm = 0; tm < 2; tm++) {
            float rmn[16], rmx[16];
#pragma unroll
            for (int r = 0; r < 16; r++) {
                int row_l = wm * 64 + tm * 32 + (r & 3) + 8 * (r >> 2) + rbase;
                int il = labi[row_l];
                float v0 = acc[tm][0][r], v1 = acc[tm][1][r];
                bool sm0 = (jl0 == il), sm1 = (jl1 == il);
                float a0 = sm0 ? v0 : INF, d0 = sm0 ? -INF : v0;
                float a1 = sm1 ? v1 : INF, d1 = sm1 ? -INF : v1;
                rmn[r] = fminf(a0, a1);
                rmx[r] = fmaxf(d0, d1);
                mnJ0 = fminf(mnJ0, a0); mxJ0 = fmaxf(mxJ0, d0);
                mnJ1 = fminf(mnJ1, a1); mxJ1 = fmaxf(mxJ1, d1);
            }
#pragma unroll
            for (int r = 0; r < 16; r++)
#pragma unroll
                for (int s = 1; s < 32; s <<= 1) {
                    rmn[r] = fminf(rmn[r], __shfl_xor(rmn[r], s, 64));
                    rmx[r] = fmaxf(rmx[r], __shfl_xor(rmx[r], s, 64));
                }
            if (cl == 0) {
#pragma unroll
                for (int r = 0; r < 16; r++) {
                    int row_l = wm * 64 + tm * 32 + (r & 3) + 8 * (r >> 2) + rbase;
                    redImn[row_l][wn] = rmn[r];
                    redA[row_l][wn] = rmx[r];
                }
            }
        }
        mnJ0 = fminf(mnJ0, __shfl_xor(mnJ0, 32, 64));
        mnJ1 = fminf(mnJ1, __shfl_xor(mnJ1, 32, 64));
        mxJ0 = fmaxf(mxJ0, __shfl_xor(mxJ0, 32, 64));
        mxJ1 = fmaxf(mxJ1, __shfl_xor(mxJ1, 32, 64));
        if (hi == 0) {
            redJmn[wn * 64 + cl][wm] = mnJ0;
            redJmn[wn * 64 + 32 + cl][wm] = mnJ1;
            redB[wn * 64 + cl][wm] = mxJ0;
            redB[wn * 64 + 32 + cl][wm] = mxJ1;
        }
        __syncthreads();
        if (t < 128) {
            atomicMin(&minEnc[ibase + t], enc_f(fminf(redImn[t][0], redImn[t][1])));
            atomicMax(&maxEnc[ibase + t], enc_f(fmaxf(redA[t][0], redA[t][1])));
            atomicMin(&minEnc[jbase + t], enc_f(fminf(redJmn[t][0], redJmn[t][1])));
            atomicMax(&maxEnc[jbase + t], enc_f(fmaxf(redB[t][0], redB[t][1])));
        }
    }
}

// 32 blocks; one float atomicAdd per block into pre-zeroed out[0].
__global__ __launch_bounds__(256) void finalize_kernel(const unsigned* __restrict__ minEnc,
                                                       const unsigned* __restrict__ maxEnc,
                                                       const float* __restrict__ cePartial,
                                                       float* __restrict__ out) {
    int gid = blockIdx.x * 256 + threadIdx.x;   // 8192 threads total
    float mn = dec_f(minEnc[gid]);
    float mxv = dec_f(maxEnc[gid]);
    // pos - neg = 2*(max_diff G - min_same G); sq_i cancels, sq_j ≈ 1 (dev ~1e-7)
    float s = fmaxf(2.0f * (mxv - mn) + MARGIN_F, 0.f);
    if (gid < ROWSTAT_BLOCKS) s += cePartial[gid];
#pragma unroll
    for (int sh = 1; sh < 64; sh <<= 1) s += __shfl_xor(s, sh, 64);
    __shared__ float red[4];
    int w = threadIdx.x >> 6, l = threadIdx.x & 63;
    if (l == 0) red[w] = s;
    __syncthreads();
    if (threadIdx.x == 0)
        atomicAdd(out, (red[0] + red[1] + red[2] + red[3]) * (1.0f / (float)N_ROWS));
}

extern "C" void kernel_launch(void* const* d_in, const int* in_sizes, int n_in,
                              void* d_out, int out_size, void* d_ws, size_t ws_size,
                              hipStream_t stream) {
    const float* x = (const float*)d_in[0];
    const int* label = (const int*)d_in[1];
    float* out = (float*)d_out;

    char* ws = (char*)d_ws;
    unsigned char* a8 = (unsigned char*)ws;                      // 4 MB fp8 sorted copy
    char* p = ws + (size_t)N_ROWS * DIM;
    unsigned* minEnc = (unsigned*)p;            p += N_ROWS * 4;
    unsigned* maxEnc = (unsigned*)p;            p += N_ROWS * 4;
    float* cePartial = (float*)p;               p += ROWSTAT_BLOCKS * 4;
    int* offsetArr = (int*)p;                   p += NLAB * 4;
    int* cnt = (int*)p;                         p += NLAB * 4;
    int* sortedLabel = (int*)p;                 p += N_ROWS * 4;

    histscan_kernel<<<1, 512, 0, stream>>>(label, offsetArr, cnt, out);
    rowstats_kernel<<<ROWSTAT_BLOCKS, 256, 0, stream>>>(x, label, offsetArr, cnt, a8,
                                                        sortedLabel, cePartial, minEnc, maxEnc);
    gemm_kernel<<<NTILE, 256, 0, stream>>>(a8, sortedLabel, minEnc, maxEnc);
    finalize_kernel<<<32, 256, 0, stream>>>(minEnc, maxEnc, cePartial, out);
}

// Round 4
// 114.685 us; speedup vs baseline: 1.3210x; 1.0179x over previous
//
#include <hip/hip_runtime.h>
#include <hip/hip_bf16.h>
#include <stdint.h>

#define N_ROWS 8192
#define DIM 512
#define NLAB 512
#define MARGIN_F 0.35f
#define NBLK 64                        // 8192/128 row-blocks
#define NPURE 1953                     // tiles with bi-bj >= 2
#define NDIAG 127                      // diagonal (64) + subdiagonal (63)
#define NTILE (NPURE + NDIAG)          // 2080
#define ROWSTAT_BLOCKS (N_ROWS / 4)    // 2048

typedef __attribute__((ext_vector_type(4))) float floatx4;
typedef __attribute__((ext_vector_type(16))) float floatx16;
typedef __attribute__((ext_vector_type(8))) int intx8;

// order-preserving float->uint map (for atomicMin/Max on floats)
__device__ __forceinline__ unsigned enc_f(float f) {
    unsigned u = __float_as_uint(f);
    return (u & 0x80000000u) ? ~u : (u | 0x80000000u);
}
__device__ __forceinline__ float dec_f(unsigned e) {
    unsigned u = (e & 0x80000000u) ? (e ^ 0x80000000u) : ~e;
    return __uint_as_float(u);
}

__device__ __forceinline__ void load_lds16(const void* g, void* l) {
    __builtin_amdgcn_global_load_lds((__attribute__((address_space(1))) void*)(void*)g,
                                     (__attribute__((address_space(3))) void*)l, 16, 0, 0);
}

// Single block: histogram of labels + exclusive scan -> offsets, zero rank counters + out.
__global__ __launch_bounds__(512) void histscan_kernel(const int* __restrict__ label,
                                                       int* __restrict__ offsetArr,
                                                       int* __restrict__ cnt,
                                                       float* __restrict__ out) {
    __shared__ int h[NLAB];
    __shared__ int sc[NLAB];
    int t = threadIdx.x;
    h[t] = 0;
    __syncthreads();
    for (int i = t; i < N_ROWS; i += 512) atomicAdd(&h[label[i]], 1);
    __syncthreads();
    int v = h[t];
    sc[t] = v;
    __syncthreads();
    for (int d = 1; d < NLAB; d <<= 1) {
        int add = (t >= d) ? sc[t - d] : 0;
        __syncthreads();
        sc[t] += add;
        __syncthreads();
    }
    offsetArr[t] = sc[t] - v;   // exclusive prefix
    cnt[t] = 0;
    if (t == 0) out[0] = 0.f;
}

// One wave per row: CE partial + fp8(e4m3) conversion scattered to label-sorted position.
// Also initializes minEnc/maxEnc.
__global__ __launch_bounds__(256) void rowstats_kernel(const float* __restrict__ x,
                                                       const int* __restrict__ label,
                                                       const int* __restrict__ offsetArr,
                                                       int* __restrict__ cnt,
                                                       unsigned char* __restrict__ a8,
                                                       int* __restrict__ sortedLabel,
                                                       float* __restrict__ cePartial,
                                                       unsigned* __restrict__ minEnc,
                                                       unsigned* __restrict__ maxEnc) {
    int gid = blockIdx.x * 256 + threadIdx.x;
    if (gid < N_ROWS) { minEnc[gid] = 0xFFFFFFFFu; maxEnc[gid] = 0u; }

    int w = threadIdx.x >> 6;
    int row = blockIdx.x * 4 + w;
    int l = threadIdx.x & 63;
    const float* xr = x + (size_t)row * DIM;
    float4 v0 = ((const float4*)xr)[2 * l];
    float4 v1 = ((const float4*)xr)[2 * l + 1];
    float vals[8] = {v0.x, v0.y, v0.z, v0.w, v1.x, v1.y, v1.z, v1.w};

    float mx = vals[0];
#pragma unroll
    for (int i = 1; i < 8; i++) mx = fmaxf(mx, vals[i]);
#pragma unroll
    for (int s = 1; s < 64; s <<= 1) mx = fmaxf(mx, __shfl_xor(mx, s, 64));

    float se = 0.f;
#pragma unroll
    for (int i = 0; i < 8; i++) se += expf(vals[i] - mx);
#pragma unroll
    for (int s = 1; s < 64; s <<= 1) se += __shfl_xor(se, s, 64);

    // sorted position for this row (counting-sort rank)
    int pos = 0;
    if (l == 0) {
        int lab = label[row];
        pos = offsetArr[lab] + atomicAdd(&cnt[lab], 1);
        sortedLabel[pos] = lab;
    }
    pos = __shfl(pos, 0, 64);

    // pack 8 fp8 e4m3 and store 8B to the sorted slot
    int w0 = __builtin_amdgcn_cvt_pk_fp8_f32(vals[0], vals[1], 0, false);
    w0 = __builtin_amdgcn_cvt_pk_fp8_f32(vals[2], vals[3], w0, true);
    int w1 = __builtin_amdgcn_cvt_pk_fp8_f32(vals[4], vals[5], 0, false);
    w1 = __builtin_amdgcn_cvt_pk_fp8_f32(vals[6], vals[7], w1, true);
    ((uint2*)(a8 + (size_t)pos * DIM))[l] = make_uint2((unsigned)w0, (unsigned)w1);

    __shared__ float wsum[4];
    if (l == 0) {
        float tl = xr[label[row]];
        wsum[w] = mx + logf(se) - tl;
    }
    __syncthreads();
    if (threadIdx.x == 0)
        cePartial[blockIdx.x] = wsum[0] + wsum[1] + wsum[2] + wsum[3];
}

// Merged GEMM on fp8. R4: R3 geometry (32x32x64 MX MFMA, BK=64, 32 KB dbuf,
// 4 blocks/CU) with the T4 counted-vmcnt schedule replacing __syncthreads:
//   prologue: STAGE(0,b0); STAGE(1,b1); __syncthreads (one-time drain; also
//             publishes diag labels).
//   iter kk:  frag ds_reads + 4 MFMA (buf cur)
//             s_barrier                     // all waves done READING buf[cur]
//             STAGE(kk+2 -> buf[cur])       // overwrite dead buffer
//             s_waitcnt vmcnt(4)            // own stage(kk+1) landed; 4 in flight
//             sched_barrier(0); s_barrier   // everyone's stage(kk+1) landed
//   Loads stay 4-8 deep in flight for the whole loop; no vmcnt(0) drain
//   anywhere in steady state (kk=6 drains to 0 once, covered by prior phase).
// R0-R3 post-mortems: every __syncthreads-based variant exposes a full L2/HBM
// round-trip per iteration (R3: 50.3 us vs ~13-15 us pipe-busy floor).
__global__ __launch_bounds__(256, 4) void gemm_kernel(const unsigned char* __restrict__ A,
                                                      const int* __restrict__ sortedLabel,
                                                      unsigned* __restrict__ minEnc,
                                                      unsigned* __restrict__ maxEnc) {
    __shared__ unsigned char As[2][128 * 64];   // 2 x 8 KB
    __shared__ unsigned char Bs[2][128 * 64];   // 2 x 8 KB
    __shared__ float redA[128][2], redB[128][2];       // Imx / Jmx
    __shared__ float redImn[128][2], redJmn[128][2];   // Imn / Jmn (diag only)
    __shared__ int labi[128], labj[128];               // labels (diag only)

    int b = blockIdx.x;
    bool diag = (b < NDIAG);
    int bi, bj;
    if (diag) {
        bi = (b < 64) ? b : (b - 63);
        bj = (b < 64) ? b : (b - 64);
    } else {
        int p = b - NDIAG;
        int ci = (int)((sqrtf(8.0f * (float)p + 1.0f) - 1.0f) * 0.5f);
        while ((ci + 1) * (ci + 2) / 2 <= p) ci++;
        while (ci * (ci + 1) / 2 > p) ci--;
        bj = p - ci * (ci + 1) / 2;
        bi = ci + 2;
    }
    int ibase = bi * 128, jbase = bj * 128;

    int t = threadIdx.x;
    int w = t >> 6, l = t & 63;
    int wm = w >> 1, wn = w & 1;
    int cl = l & 31;        // col/row lane within a 32x32 frag
    int hi = l >> 5;        // k-half select

    // diag: label loads issued early; prologue __syncthreads publishes them.
    if (diag) {
        if (t < 128) labi[t] = sortedLabel[ibase + t];
        else labj[t - 128] = sortedLabel[jbase + t - 128];
    }

    floatx16 acc[2][2];
#pragma unroll
    for (int a = 0; a < 2; a++)
#pragma unroll
        for (int c = 0; c < 2; c++) acc[a][c] = (floatx16)0.f;

    // Staging geometry: slot s = t + 256*i covers 512 slots of 16B = 8 KB tile.
    // LDS layout linear (gl_lds requirement); SOURCE pre-swizzled so that the
    // stored chunk at row r, slot c holds logical chunk c ^ ((r>>1)&3).
    int s0 = t, s1 = t + 256;
    int r0_ = s0 >> 2, r1_ = s1 >> 2;
    int c0_ = (s0 & 3) ^ ((r0_ >> 1) & 3);
    int c1_ = (s1 & 3) ^ ((r1_ >> 1) & 3);
    const unsigned char* srcA0 = A + (size_t)(ibase + r0_) * DIM + c0_ * 16;
    const unsigned char* srcA1 = A + (size_t)(ibase + r1_) * DIM + c1_ * 16;
    const unsigned char* srcB0 = A + (size_t)(jbase + r0_) * DIM + c0_ * 16;
    const unsigned char* srcB1 = A + (size_t)(jbase + r1_) * DIM + c1_ * 16;
    int ldo0 = s0 * 16, ldo1 = s1 * 16;

#define STAGE(KK, BUF)                                      \
    {                                                       \
        load_lds16(srcA0 + (KK) * 64, As[BUF] + ldo0);      \
        load_lds16(srcA1 + (KK) * 64, As[BUF] + ldo1);      \
        load_lds16(srcB0 + (KK) * 64, Bs[BUF] + ldo0);      \
        load_lds16(srcB1 + (KK) * 64, Bs[BUF] + ldo1);      \
    }

    STAGE(0, 0);
    STAGE(1, 1);
    __syncthreads();   // one-time drain: buf0 (and labels) ready; buf1 may or
                       // may not have landed (drained too — counting below
                       // remains valid: vmcnt(4) checks are conservative).

#pragma unroll
    for (int kk = 0; kk < 8; kk++) {
        int cur = kk & 1;

        // B fragments: lane holds col cl of j-rows, k = hi*32..hi*32+31 (2 chunks)
        intx8 b0, b1;
        {
            int r = wn * 64 + cl;
            int f = (r >> 1) & 3;
            const int4* rp = (const int4*)(Bs[cur] + r * 64);
            int4 lo = rp[(2 * hi) ^ f];
            int4 h4 = rp[(2 * hi + 1) ^ f];
            b0[0] = lo.x; b0[1] = lo.y; b0[2] = lo.z; b0[3] = lo.w;
            b0[4] = h4.x; b0[5] = h4.y; b0[6] = h4.z; b0[7] = h4.w;
        }
        {
            int r = wn * 64 + 32 + cl;
            int f = (r >> 1) & 3;
            const int4* rp = (const int4*)(Bs[cur] + r * 64);
            int4 lo = rp[(2 * hi) ^ f];
            int4 h4 = rp[(2 * hi + 1) ^ f];
            b1[0] = lo.x; b1[1] = lo.y; b1[2] = lo.z; b1[3] = lo.w;
            b1[4] = h4.x; b1[5] = h4.y; b1[6] = h4.z; b1[7] = h4.w;
        }
#pragma unroll
        for (int tm = 0; tm < 2; tm++) {
            int r = wm * 64 + tm * 32 + cl;
            int f = (r >> 1) & 3;
            const int4* rp = (const int4*)(As[cur] + r * 64);
            int4 lo = rp[(2 * hi) ^ f];
            int4 h4 = rp[(2 * hi + 1) ^ f];
            intx8 a;
            a[0] = lo.x; a[1] = lo.y; a[2] = lo.z; a[3] = lo.w;
            a[4] = h4.x; a[5] = h4.y; a[6] = h4.z; a[7] = h4.w;
            acc[tm][0] = __builtin_amdgcn_mfma_scale_f32_32x32x64_f8f6f4(
                a, b0, acc[tm][0], 0, 0, 0, 0x7F7F7F7F, 0, 0x7F7F7F7F);
            acc[tm][1] = __builtin_amdgcn_mfma_scale_f32_32x32x64_f8f6f4(
                a, b1, acc[tm][1], 0, 0, 0, 0x7F7F7F7F, 0, 0x7F7F7F7F);
        }

        if (kk < 7) {
            __builtin_amdgcn_s_barrier();      // all waves done reading buf[cur]
            if (kk < 6) STAGE(kk + 2, cur);    // overwrite dead buffer
            if (kk < 6) {
                asm volatile("s_waitcnt vmcnt(4)" ::: "memory");   // stage(kk+1) landed
            } else {
                asm volatile("s_waitcnt vmcnt(0)" ::: "memory");   // stage(7) landed
            }
            __builtin_amdgcn_sched_barrier(0);
            __builtin_amdgcn_s_barrier();      // everyone's stage(kk+1) landed
        }
    }
#undef STAGE

    // C/D layout 32x32: col = lane&31, row = (reg&3) + 8*(reg>>2) + 4*(lane>>5)
    const float INF = __builtin_inff();
    int rbase = 4 * hi;   // row contribution of the lane's k-half

    if (!diag) {
        // ---- max-only epilogue ----
        float mxJ0 = -INF, mxJ1 = -INF;
#pragma unroll
        for (int tm = 0; tm < 2; tm++) {
            float rm[16];
#pragma unroll
            for (int r = 0; r < 16; r++) {
                float v0 = acc[tm][0][r], v1 = acc[tm][1][r];
                rm[r] = fmaxf(v0, v1);
                mxJ0 = fmaxf(mxJ0, v0);
                mxJ1 = fmaxf(mxJ1, v1);
            }
#pragma unroll
            for (int r = 0; r < 16; r++)
#pragma unroll
                for (int s = 1; s < 32; s <<= 1)
                    rm[r] = fmaxf(rm[r], __shfl_xor(rm[r], s, 64));
            if (cl == 0) {
#pragma unroll
                for (int r = 0; r < 16; r++)
                    redA[wm * 64 + tm * 32 + (r & 3) + 8 * (r >> 2) + rbase][wn] = rm[r];
            }
        }
        mxJ0 = fmaxf(mxJ0, __shfl_xor(mxJ0, 32, 64));
        mxJ1 = fmaxf(mxJ1, __shfl_xor(mxJ1, 32, 64));
        if (hi == 0) {
            redB[wn * 64 + cl][wm] = mxJ0;
            redB[wn * 64 + 32 + cl][wm] = mxJ1;
        }
        __syncthreads();
        if (t < 128) {
            atomicMax(&maxEnc[ibase + t], enc_f(fmaxf(redA[t][0], redA[t][1])));
            atomicMax(&maxEnc[jbase + t], enc_f(fmaxf(redB[t][0], redB[t][1])));
        }
    } else {
        // ---- mixed epilogue (min-same / max-diff) ----
        int jl0 = labj[wn * 64 + cl];
        int jl1 = labj[wn * 64 + 32 + cl];
        float mnJ0 = INF, mnJ1 = INF, mxJ0 = -INF, mxJ1 = -INF;
#pragma unroll
        for (int tm = 0; tm < 2; tm++) {
            float rmn[16], rmx[16];
#pragma unroll
            for (int r = 0; r < 16; r++) {
                int row_l = wm * 64 + tm * 32 + (r & 3) + 8 * (r >> 2) + rbase;
                int il = labi[row_l];
                float v0 = acc[tm][0][r], v1 = acc[tm][1][r];
                bool sm0 = (jl0 == il), sm1 = (jl1 == il);
                float a0 = sm0 ? v0 : INF, d0 = sm0 ? -INF : v0;
                float a1 = sm1 ? v1 : INF, d1 = sm1 ? -INF : v1;
                rmn[r] = fminf(a0, a1);
                rmx[r] = fmaxf(d0, d1);
                mnJ0 = fminf(mnJ0, a0); mxJ0 = fmaxf(mxJ0, d0);
                mnJ1 = fminf(mnJ1, a1); mxJ1 = fmaxf(mxJ1, d1);
            }
#pragma unroll
            for (int r = 0; r < 16; r++)
#pragma unroll
                for (int s = 1; s < 32; s <<= 1) {
                    rmn[r] = fminf(rmn[r], __shfl_xor(rmn[r], s, 64));
                    rmx[r] = fmaxf(rmx[r], __shfl_xor(rmx[r], s, 64));
                }
            if (cl == 0) {
#pragma unroll
                for (int r = 0; r < 16; r++) {
                    int row_l = wm * 64 + tm * 32 + (r & 3) + 8 * (r >> 2) + rbase;
                    redImn[row_l][wn] = rmn[r];
                    redA[row_l][wn] = rmx[r];
                }
            }
        }
        mnJ0 = fminf(mnJ0, __shfl_xor(mnJ0, 32, 64));
        mnJ1 = fminf(mnJ1, __shfl_xor(mnJ1, 32, 64));
        mxJ0 = fmaxf(mxJ0, __shfl_xor(mxJ0, 32, 64));
        mxJ1 = fmaxf(mxJ1, __shfl_xor(mxJ1, 32, 64));
        if (hi == 0) {
            redJmn[wn * 64 + cl][wm] = mnJ0;
            redJmn[wn * 64 + 32 + cl][wm] = mnJ1;
            redB[wn * 64 + cl][wm] = mxJ0;
            redB[wn * 64 + 32 + cl][wm] = mxJ1;
        }
        __syncthreads();
        if (t < 128) {
            atomicMin(&minEnc[ibase + t], enc_f(fminf(redImn[t][0], redImn[t][1])));
            atomicMax(&maxEnc[ibase + t], enc_f(fmaxf(redA[t][0], redA[t][1])));
            atomicMin(&minEnc[jbase + t], enc_f(fminf(redJmn[t][0], redJmn[t][1])));
            atomicMax(&maxEnc[jbase + t], enc_f(fmaxf(redB[t][0], redB[t][1])));
        }
    }
}

// 32 blocks; one float atomicAdd per block into pre-zeroed out[0].
__global__ __launch_bounds__(256) void finalize_kernel(const unsigned* __restrict__ minEnc,
                                                       const unsigned* __restrict__ maxEnc,
                                                       const float* __restrict__ cePartial,
                                                       float* __restrict__ out) {
    int gid = blockIdx.x * 256 + threadIdx.x;   // 8192 threads total
    float mn = dec_f(minEnc[gid]);
    float mxv = dec_f(maxEnc[gid]);
    // pos - neg = 2*(max_diff G - min_same G); sq_i cancels, sq_j ≈ 1 (dev ~1e-7)
    float s = fmaxf(2.0f * (mxv - mn) + MARGIN_F, 0.f);
    if (gid < ROWSTAT_BLOCKS) s += cePartial[gid];
#pragma unroll
    for (int sh = 1; sh < 64; sh <<= 1) s += __shfl_xor(s, sh, 64);
    __shared__ float red[4];
    int w = threadIdx.x >> 6, l = threadIdx.x & 63;
    if (l == 0) red[w] = s;
    __syncthreads();
    if (threadIdx.x == 0)
        atomicAdd(out, (red[0] + red[1] + red[2] + red[3]) * (1.0f / (float)N_ROWS));
}

extern "C" void kernel_launch(void* const* d_in, const int* in_sizes, int n_in,
                              void* d_out, int out_size, void* d_ws, size_t ws_size,
                              hipStream_t stream) {
    const float* x = (const float*)d_in[0];
    const int* label = (const int*)d_in[1];
    float* out = (float*)d_out;

    char* ws = (char*)d_ws;
    unsigned char* a8 = (unsigned char*)ws;                      // 4 MB fp8 sorted copy
    char* p = ws + (size_t)N_ROWS * DIM;
    unsigned* minEnc = (unsigned*)p;            p += N_ROWS * 4;
    unsigned* maxEnc = (unsigned*)p;            p += N_ROWS * 4;
    float* cePartial = (float*)p;               p += ROWSTAT_BLOCKS * 4;
    int* offsetArr = (int*)p;                   p += NLAB * 4;
    int* cnt = (int*)p;                         p += NLAB * 4;
    int* sortedLabel = (int*)p;                 p += N_ROWS * 4;

    histscan_kernel<<<1, 512, 0, stream>>>(label, offsetArr, cnt, out);
    rowstats_kernel<<<ROWSTAT_BLOCKS, 256, 0, stream>>>(x, label, offsetArr, cnt, a8,
                                                        sortedLabel, cePartial, minEnc, maxEnc);
    gemm_kernel<<<NTILE, 256, 0, stream>>>(a8, sortedLabel, minEnc, maxEnc);
    finalize_kernel<<<32, 256, 0, stream>>>(minEnc, maxEnc, cePartial, out);
}